// Round 1
// baseline (514.439 us; speedup 1.0000x reference)
//
#include <hip/hip_runtime.h>

#define NB 8
#define NT 256
#define NL 64
#define ND 768

__device__ __forceinline__ float dot4(float4 a, float4 b) {
    return a.x*b.x + a.y*b.y + a.z*b.z + a.w*b.w;
}

// ---------------- Kernel 1: k/v projections (fp32 tiled GEMM) ----------------
// k[m,e] = sum_d E[m,d] * W[e,d]  (both operands row-major along d)
__global__ __launch_bounds__(256) void proj_kernel(
    const float* __restrict__ E, const float* __restrict__ Wk,
    const float* __restrict__ Wv, float* __restrict__ kws,
    float* __restrict__ vws)
{
    const float* W = (blockIdx.z == 0) ? Wk : Wv;
    float* O       = (blockIdx.z == 0) ? kws : vws;

    __shared__ float As[16][68];
    __shared__ float Bs[16][68];

    const int tid = threadIdx.x;
    const int m0 = blockIdx.x * 64;
    const int e0 = blockIdx.y * 64;
    const int ty = tid >> 4;      // 0..15 -> m quad
    const int tx = tid & 15;      // 0..15 -> e quad
    const int mm = tid >> 2;      // 0..63 staging row
    const int c4 = tid & 3;       // 0..3 staging k-quad

    float acc[4][4];
    #pragma unroll
    for (int i = 0; i < 4; ++i)
        #pragma unroll
        for (int j = 0; j < 4; ++j) acc[i][j] = 0.f;

    for (int k0 = 0; k0 < ND; k0 += 16) {
        float4 a = *(const float4*)(E + (size_t)(m0 + mm) * ND + k0 + c4 * 4);
        float4 b = *(const float4*)(W + (size_t)(e0 + mm) * ND + k0 + c4 * 4);
        As[c4*4+0][mm] = a.x; As[c4*4+1][mm] = a.y;
        As[c4*4+2][mm] = a.z; As[c4*4+3][mm] = a.w;
        Bs[c4*4+0][mm] = b.x; Bs[c4*4+1][mm] = b.y;
        Bs[c4*4+2][mm] = b.z; Bs[c4*4+3][mm] = b.w;
        __syncthreads();
        #pragma unroll
        for (int kk = 0; kk < 16; ++kk) {
            float4 av = *(const float4*)&As[kk][ty * 4];
            float4 bv = *(const float4*)&Bs[kk][tx * 4];
            float a4[4] = {av.x, av.y, av.z, av.w};
            float b4[4] = {bv.x, bv.y, bv.z, bv.w};
            #pragma unroll
            for (int i = 0; i < 4; ++i)
                #pragma unroll
                for (int j = 0; j < 4; ++j) acc[i][j] += a4[i] * b4[j];
        }
        __syncthreads();
    }
    #pragma unroll
    for (int i = 0; i < 4; ++i) {
        float4 o;
        o.x = acc[i][0]; o.y = acc[i][1]; o.z = acc[i][2]; o.w = acc[i][3];
        *(float4*)(O + (size_t)(m0 + ty * 4 + i) * ND + e0 + tx * 4) = o;
    }
}

// ---------------- Kernel 2: segmented linear attention ----------------
// One workgroup per (b,t).
__global__ __launch_bounds__(256) void attn_kernel(
    const int* __restrict__ spk, const float* __restrict__ tok,
    const float* __restrict__ kws, const float* __restrict__ vws,
    float* __restrict__ out)
{
    __shared__ int   mlist[NT];
    __shared__ int   wavecnt[4];
    __shared__ float Smat[64][65];
    __shared__ float ubuf[64 * 196];   // union: v-tile [64][68] / k-strip [64][196]

    float (*vt)[68]   = (float (*)[68])ubuf;
    float (*kst)[196] = (float (*)[196])ubuf;

    const int bt  = blockIdx.x;
    const int b   = bt >> 8;
    const int t   = bt & 255;
    const int tid = threadIdx.x;

    // ---- Phase 0: build same-speaker prefix list (ballot + prefix sum) ----
    const int tgt = spk[b * NT + t];
    int my = -1;
    if (tid <= t) my = spk[b * NT + tid];
    const bool match = (tid <= t) && (my == tgt);
    unsigned long long bal = __ballot(match);
    const int lane = tid & 63, w = tid >> 6;
    if (lane == 0) wavecnt[w] = __popcll(bal);
    __syncthreads();
    int off = 0;
    #pragma unroll
    for (int ww = 0; ww < 4; ++ww) if (ww < w) off += wavecnt[ww];
    const int n = wavecnt[0] + wavecnt[1] + wavecnt[2] + wavecnt[3];
    const int before = __popcll(bal & ((1ull << lane) - 1ull));
    if (match) mlist[off + before] = tid;
    __syncthreads();

    const int l = tid >> 2;       // 0..63 output row
    const int q = tid & 3;        // 0..3  d-split
    const float* tokrow = tok + ((size_t)bt * NL + l) * ND;

    for (int j0 = 0; j0 < n; j0 += 64) {
        const int nc = min(64, n - j0);

        // ---- Phase 1: S[l][j] = tok[l] . v[j], d-tiled ----
        float acc[64];
        #pragma unroll
        for (int j = 0; j < 64; ++j) acc[j] = 0.f;

        for (int dt = 0; dt < 12; ++dt) {
            for (int idx = tid; idx < nc * 16; idx += 256) {
                const int jj = idx >> 4, c = idx & 15;
                float4 vv = *(const float4*)(vws +
                    ((size_t)b * NT + mlist[j0 + jj]) * ND + dt * 64 + c * 4);
                *(float4*)&vt[jj][c * 4] = vv;
            }
            __syncthreads();
            float4 tr[4];
            #pragma unroll
            for (int ii = 0; ii < 4; ++ii)
                tr[ii] = *(const float4*)(tokrow + dt * 64 + q * 16 + ii * 4);
            #pragma unroll
            for (int j = 0; j < 64; ++j) {
                if (j < nc) {
                    const float4* vr = (const float4*)&vt[j][q * 16];
                    float4 v0 = vr[0], v1 = vr[1], v2 = vr[2], v3 = vr[3];
                    acc[j] += dot4(tr[0], v0) + dot4(tr[1], v1) +
                              dot4(tr[2], v2) + dot4(tr[3], v3);
                }
            }
            __syncthreads();
        }
        // reduce the 4 d-partials per (l,j) across the 4-lane group
        #pragma unroll
        for (int j = 0; j < 64; ++j) {
            float s = acc[j];
            s += __shfl_xor(s, 1);
            s += __shfl_xor(s, 2);
            if (q == 0) Smat[l][j] = s;
        }
        __syncthreads();

        // ---- Phase 2: out[l][d] = tok[l][d] + sum_j S[l][j]*k[j][d] ----
        for (int strip = 0; strip < 4; ++strip) {
            for (int idx = tid; idx < nc * 48; idx += 256) {
                const int jj = idx / 48, c = idx % 48;
                float4 kv = *(const float4*)(kws +
                    ((size_t)b * NT + mlist[j0 + jj]) * ND + strip * 192 + c * 4);
                *(float4*)&kst[jj][c * 4] = kv;
            }
            __syncthreads();

            float* op = out + ((size_t)bt * NL + l) * ND + strip * 192 + q * 48;
            const float* tp = tokrow + strip * 192 + q * 48;
            float4 a[12];
            if (j0 == 0) {
                #pragma unroll
                for (int ii = 0; ii < 12; ++ii) a[ii] = *(const float4*)(tp + ii * 4);
            } else {
                #pragma unroll
                for (int ii = 0; ii < 12; ++ii) a[ii] = *(const float4*)(op + ii * 4);
            }
            for (int j = 0; j < nc; ++j) {
                const float s = Smat[l][j];
                const float4* kr = (const float4*)&kst[j][q * 48];
                #pragma unroll
                for (int ii = 0; ii < 12; ++ii) {
                    float4 kv = kr[ii];
                    a[ii].x += s * kv.x; a[ii].y += s * kv.y;
                    a[ii].z += s * kv.z; a[ii].w += s * kv.w;
                }
            }
            #pragma unroll
            for (int ii = 0; ii < 12; ++ii) *(float4*)(op + ii * 4) = a[ii];
            __syncthreads();
        }
    }
}

extern "C" void kernel_launch(void* const* d_in, const int* in_sizes, int n_in,
                              void* d_out, int out_size, void* d_ws, size_t ws_size,
                              hipStream_t stream) {
    const int*   spk = (const int*)d_in[1];
    const float* tok = (const float*)d_in[2];
    const float* edu = (const float*)d_in[3];
    const float* Wk  = (const float*)d_in[4];
    const float* Wv  = (const float*)d_in[5];
    float* kws = (float*)d_ws;
    float* vws = kws + (size_t)NB * NT * ND;
    float* out = (float*)d_out;

    dim3 g1(2048 / 64, ND / 64, 2);
    proj_kernel<<<g1, 256, 0, stream>>>(edu, Wk, Wv, kws, vws);
    attn_kernel<<<NB * NT, 256, 0, stream>>>(spk, tok, kws, vws, out);
}

// Round 2
// 477.687 us; speedup vs baseline: 1.0769x; 1.0769x over previous
//
#include <hip/hip_runtime.h>

#define NB 8
#define NT 256
#define NL 64
#define ND 768

typedef __attribute__((ext_vector_type(4))) float f32x4;
typedef __attribute__((ext_vector_type(8))) short bf16x8;

__device__ __forceinline__ ushort f2bf(float f) {
    union { float f; unsigned u; } x; x.f = f;
    unsigned u = x.u;
    return (ushort)((u + 0x7fffu + ((u >> 16) & 1u)) >> 16);
}

// ---------------- Kernel 1: k/v projections (fp32 tiled GEMM) ----------------
__global__ __launch_bounds__(256) void proj_kernel(
    const float* __restrict__ E, const float* __restrict__ Wk,
    const float* __restrict__ Wv, float* __restrict__ kws,
    float* __restrict__ vws)
{
    const float* W = (blockIdx.z == 0) ? Wk : Wv;
    float* O       = (blockIdx.z == 0) ? kws : vws;

    __shared__ float As[16][68];
    __shared__ float Bs[16][68];

    const int tid = threadIdx.x;
    const int m0 = blockIdx.x * 64;
    const int e0 = blockIdx.y * 64;
    const int ty = tid >> 4;
    const int tx = tid & 15;
    const int mm = tid >> 2;
    const int c4 = tid & 3;

    float acc[4][4];
    #pragma unroll
    for (int i = 0; i < 4; ++i)
        #pragma unroll
        for (int j = 0; j < 4; ++j) acc[i][j] = 0.f;

    for (int k0 = 0; k0 < ND; k0 += 16) {
        float4 a = *(const float4*)(E + (size_t)(m0 + mm) * ND + k0 + c4 * 4);
        float4 b = *(const float4*)(W + (size_t)(e0 + mm) * ND + k0 + c4 * 4);
        As[c4*4+0][mm] = a.x; As[c4*4+1][mm] = a.y;
        As[c4*4+2][mm] = a.z; As[c4*4+3][mm] = a.w;
        Bs[c4*4+0][mm] = b.x; Bs[c4*4+1][mm] = b.y;
        Bs[c4*4+2][mm] = b.z; Bs[c4*4+3][mm] = b.w;
        __syncthreads();
        #pragma unroll
        for (int kk = 0; kk < 16; ++kk) {
            float4 av = *(const float4*)&As[kk][ty * 4];
            float4 bv = *(const float4*)&Bs[kk][tx * 4];
            float a4[4] = {av.x, av.y, av.z, av.w};
            float b4[4] = {bv.x, bv.y, bv.z, bv.w};
            #pragma unroll
            for (int i = 0; i < 4; ++i)
                #pragma unroll
                for (int j = 0; j < 4; ++j) acc[i][j] += a4[i] * b4[j];
        }
        __syncthreads();
    }
    #pragma unroll
    for (int i = 0; i < 4; ++i) {
        float4 o;
        o.x = acc[i][0]; o.y = acc[i][1]; o.z = acc[i][2]; o.w = acc[i][3];
        *(float4*)(O + (size_t)(m0 + ty * 4 + i) * ND + e0 + tx * 4) = o;
    }
}

// ---------------- Kernel 2: MFMA segmented linear attention ----------------
// One workgroup (256 threads = 4 waves) per (b,t). Fixed 64 j-slots per chunk.
__global__ __launch_bounds__(256) void attn_kernel(
    const int* __restrict__ spk, const float* __restrict__ tok,
    const float* __restrict__ kws, const float* __restrict__ vws,
    float* __restrict__ out)
{
    __shared__ int mlist[NT];
    __shared__ int wavecnt[4];
    __shared__ ushort Abuf[64 * 128];   // phase1: tok tile [64][128]; phase2: kT [128][64]
    __shared__ ushort Bbuf[64 * 128];   // phase1: v tile  [64][128]
    __shared__ ushort Sbuf[64 * 64];    // S bf16 [64][64]

    const int bt  = blockIdx.x;
    const int b   = bt >> 8;
    const int t   = bt & 255;
    const int tid = threadIdx.x;

    // ---- Phase 0: same-speaker prefix list ----
    const int tgt = spk[b * NT + t];
    int my = -1;
    if (tid <= t) my = spk[b * NT + tid];
    const bool match = (tid <= t) && (my == tgt);
    unsigned long long bal = __ballot(match);
    const int lane = tid & 63, w = tid >> 6;
    if (lane == 0) wavecnt[w] = __popcll(bal);
    __syncthreads();
    int off = 0;
    #pragma unroll
    for (int ww = 0; ww < 4; ++ww) if (ww < w) off += wavecnt[ww];
    const int n = wavecnt[0] + wavecnt[1] + wavecnt[2] + wavecnt[3];
    const int before = __popcll(bal & ((1ull << lane) - 1ull));
    if (match) mlist[off + before] = tid;
    __syncthreads();

    const int fr = lane & 15;        // fragment row/col selector
    const int fq = lane >> 4;        // k-quarter
    const int srow = tid >> 5;       // staging: 0..7
    const int scol = tid & 31;       // staging: 0..31 (x4 floats)
    const int jp = (tid & 31) * 2;   // kT staging: j pair
    const int dg = tid >> 5;         // kT staging: dcol group (x16)

    const size_t tokbase = (size_t)bt * NL * ND;
    const f32x4 zero4 = {0.f, 0.f, 0.f, 0.f};

    for (int j0 = 0; j0 < n; j0 += 64) {
        // ---------------- Phase 1: S = tok @ v^T ----------------
        f32x4 accS[4];
        #pragma unroll
        for (int jt = 0; jt < 4; ++jt) accS[jt] = zero4;

        for (int dt = 0; dt < 6; ++dt) {
            #pragma unroll
            for (int p = 0; p < 8; ++p) {
                const int r = p * 8 + srow;
                float4 tv = *(const float4*)(tok + tokbase + (size_t)r * ND + dt * 128 + scol * 4);
                float4 vv = make_float4(0.f, 0.f, 0.f, 0.f);
                const int jj = j0 + r;
                if (jj < n) {
                    const int g = mlist[jj];
                    vv = *(const float4*)(vws + ((size_t)b * NT + g) * ND + dt * 128 + scol * 4);
                }
                const int idx = (r * 128 + scol * 4) ^ ((r & 7) << 3);
                ushort4 th; th.x = f2bf(tv.x); th.y = f2bf(tv.y); th.z = f2bf(tv.z); th.w = f2bf(tv.w);
                ushort4 vh; vh.x = f2bf(vv.x); vh.y = f2bf(vv.y); vh.z = f2bf(vv.z); vh.w = f2bf(vv.w);
                *(ushort4*)&Abuf[idx] = th;
                *(ushort4*)&Bbuf[idx] = vh;
            }
            __syncthreads();
            #pragma unroll
            for (int ks = 0; ks < 4; ++ks) {
                const int arow = w * 16 + fr;
                const int aidx = (arow * 128 + ks * 32 + fq * 8) ^ ((arow & 7) << 3);
                bf16x8 af = *(const bf16x8*)&Abuf[aidx];
                #pragma unroll
                for (int jt = 0; jt < 4; ++jt) {
                    const int brow = jt * 16 + fr;
                    const int bidx = (brow * 128 + ks * 32 + fq * 8) ^ ((brow & 7) << 3);
                    bf16x8 bfv = *(const bf16x8*)&Bbuf[bidx];
                    accS[jt] = __builtin_amdgcn_mfma_f32_16x16x32_bf16(af, bfv, accS[jt], 0, 0, 0);
                }
            }
            __syncthreads();
        }

        // S -> LDS bf16 (C layout: col = lane&15, row = (lane>>4)*4 + reg)
        #pragma unroll
        for (int jt = 0; jt < 4; ++jt) {
            #pragma unroll
            for (int i = 0; i < 4; ++i) {
                const int r = w * 16 + fq * 4 + i;
                const int c = jt * 16 + fr;
                Sbuf[(r * 64 + c) ^ ((r & 7) << 3)] = f2bf(accS[jt][i]);
            }
        }
        __syncthreads();

        // ---------------- Phase 2: out = base + S @ K ----------------
        const int g0 = (j0 + jp     < n) ? mlist[j0 + jp]     : -1;
        const int g1 = (j0 + jp + 1 < n) ? mlist[j0 + jp + 1] : -1;
        for (int st = 0; st < 6; ++st) {
            // stage kT [128 dcols][64 j], packed pair writes
            #pragma unroll
            for (int c4 = 0; c4 < 4; ++c4) {
                float4 k0 = make_float4(0.f, 0.f, 0.f, 0.f);
                float4 k1 = make_float4(0.f, 0.f, 0.f, 0.f);
                if (g0 >= 0) k0 = *(const float4*)(kws + ((size_t)b * NT + g0) * ND + st * 128 + dg * 16 + c4 * 4);
                if (g1 >= 0) k1 = *(const float4*)(kws + ((size_t)b * NT + g1) * ND + st * 128 + dg * 16 + c4 * 4);
                float k0a[4] = {k0.x, k0.y, k0.z, k0.w};
                float k1a[4] = {k1.x, k1.y, k1.z, k1.w};
                #pragma unroll
                for (int e = 0; e < 4; ++e) {
                    const int dc = dg * 16 + c4 * 4 + e;
                    const unsigned pack = (unsigned)f2bf(k0a[e]) | ((unsigned)f2bf(k1a[e]) << 16);
                    const int idx = (dc * 64 + jp) ^ ((dc & 7) << 3);
                    *(unsigned*)&Abuf[idx] = pack;
                }
            }
            __syncthreads();

            f32x4 acco[8];
            #pragma unroll
            for (int ct = 0; ct < 8; ++ct) acco[ct] = zero4;
            #pragma unroll
            for (int ks = 0; ks < 2; ++ks) {
                const int arow = w * 16 + fr;
                const int aidx = (arow * 64 + ks * 32 + fq * 8) ^ ((arow & 7) << 3);
                bf16x8 af = *(const bf16x8*)&Sbuf[aidx];
                #pragma unroll
                for (int ct = 0; ct < 8; ++ct) {
                    const int brow = ct * 16 + fr;
                    const int bidx = (brow * 64 + ks * 32 + fq * 8) ^ ((brow & 7) << 3);
                    bf16x8 bfv = *(const bf16x8*)&Abuf[bidx];
                    acco[ct] = __builtin_amdgcn_mfma_f32_16x16x32_bf16(af, bfv, acco[ct], 0, 0, 0);
                }
            }
            // epilogue: residual add + store
            #pragma unroll
            for (int ct = 0; ct < 8; ++ct) {
                #pragma unroll
                for (int i = 0; i < 4; ++i) {
                    const int r = w * 16 + fq * 4 + i;
                    const int dcol = st * 128 + ct * 16 + fr;
                    const size_t gidx = tokbase + (size_t)r * ND + dcol;
                    const float base = (j0 == 0) ? tok[gidx] : out[gidx];
                    out[gidx] = base + acco[ct][i];
                }
            }
            __syncthreads();
        }
    }
}

extern "C" void kernel_launch(void* const* d_in, const int* in_sizes, int n_in,
                              void* d_out, int out_size, void* d_ws, size_t ws_size,
                              hipStream_t stream) {
    const int*   spk = (const int*)d_in[1];
    const float* tok = (const float*)d_in[2];
    const float* edu = (const float*)d_in[3];
    const float* Wk  = (const float*)d_in[4];
    const float* Wv  = (const float*)d_in[5];
    float* kws = (float*)d_ws;
    float* vws = kws + (size_t)NB * NT * ND;
    float* out = (float*)d_out;

    dim3 g1(2048 / 64, ND / 64, 2);
    proj_kernel<<<g1, 256, 0, stream>>>(edu, Wk, Wv, kws, vws);
    attn_kernel<<<NB * NT, 256, 0, stream>>>(spk, tok, kws, vws, out);
}